// Round 8
// baseline (256.364 us; speedup 1.0000x reference)
//
#include <hip/hip_runtime.h>
#include <cfloat>

typedef __attribute__((ext_vector_type(8))) short short8;
typedef __attribute__((ext_vector_type(4))) float f32x4;

#define NE 1024
#define EDIM 256
#define HW 1024
#define BSTRIDE (EDIM * HW)        // 262144
#define TOTAL 8388608

// workspace layout (bytes)
#define EMBB_OFF  0                        // ushort[1024*256] bf16 = 512 KB
#define ENORM_OFF (512 * 1024)             // float[1024]
#define HIST_OFF  (ENORM_OFF + 4096)       // int[1024]
#define LOSS_OFF  (HIST_OFF + 4096)        // float[64] banked loss accum
#define GCNT_OFF  (LOSS_OFF + 256)         // int[512] per-group contributor count
#define GDONE_OFF (GCNT_OFF + 2048)        // int completion counter
#define BEST_OFF  (GDONE_OFF + 16)         // u64[32768] packed (dist,code)

#define BUFS (64 * 264)                    // shorts per B buffer (64 codes)
#define NT   4                             // tiles per block (256 codes)

// round-to-nearest-even fp32 -> bf16 bits (inputs are finite)
__device__ __forceinline__ unsigned short f2bf(float x) {
    unsigned u = __builtin_bit_cast(unsigned, x);
    return (unsigned short)((u + 0x7fffu + ((u >> 16) & 1u)) >> 16);
}

// ---------------------------------------------------------------------------
// P: emb fp32 [1024][256] -> embB bf16 rows + enorm. 64 blocks x 256 thr.
// Also inits best64 (all blocks) and hist/loss/gcnt/gdone (block 0).
// ---------------------------------------------------------------------------
__global__ void prep_emb(const float* __restrict__ emb,
                         unsigned short* __restrict__ embB,
                         float* __restrict__ enorm,
                         int* __restrict__ hist,
                         float* __restrict__ lossAcc,
                         int* __restrict__ gcnt,
                         int* __restrict__ gdone,
                         unsigned long long* __restrict__ best64) {
    int t = threadIdx.x;
    int gid = blockIdx.x * 256 + t;        // 0..16383
    int row = gid >> 4, seg = gid & 15;
    const float4* e4 = (const float4*)(emb + (size_t)row * EDIM) + seg * 4;
    float4 a0 = e4[0], a1 = e4[1], a2 = e4[2], a3 = e4[3];
    float s = a0.x * a0.x + a0.y * a0.y + a0.z * a0.z + a0.w * a0.w
            + a1.x * a1.x + a1.y * a1.y + a1.z * a1.z + a1.w * a1.w
            + a2.x * a2.x + a2.y * a2.y + a2.z * a2.z + a2.w * a2.w
            + a3.x * a3.x + a3.y * a3.y + a3.z * a3.z + a3.w * a3.w;
    short8 v0, v1;
    v0[0] = (short)f2bf(a0.x); v0[1] = (short)f2bf(a0.y);
    v0[2] = (short)f2bf(a0.z); v0[3] = (short)f2bf(a0.w);
    v0[4] = (short)f2bf(a1.x); v0[5] = (short)f2bf(a1.y);
    v0[6] = (short)f2bf(a1.z); v0[7] = (short)f2bf(a1.w);
    v1[0] = (short)f2bf(a2.x); v1[1] = (short)f2bf(a2.y);
    v1[2] = (short)f2bf(a2.z); v1[3] = (short)f2bf(a2.w);
    v1[4] = (short)f2bf(a3.x); v1[5] = (short)f2bf(a3.y);
    v1[6] = (short)f2bf(a3.z); v1[7] = (short)f2bf(a3.w);
    *(short8*)&embB[(size_t)row * EDIM + seg * 16]     = v0;
    *(short8*)&embB[(size_t)row * EDIM + seg * 16 + 8] = v1;
    s += __shfl_xor(s, 1, 64);
    s += __shfl_xor(s, 2, 64);
    s += __shfl_xor(s, 4, 64);
    s += __shfl_xor(s, 8, 64);
    if (seg == 0) enorm[row] = s;
    // best64 init: 64 blocks x 256 thr x 2 = 32768
    size_t b0 = (size_t)blockIdx.x * 512 + (size_t)t * 2;
    best64[b0] = ~0ULL; best64[b0 + 1] = ~0ULL;
    if (blockIdx.x == 0) {
        ((int4*)hist)[t] = (int4){0, 0, 0, 0};
        if (t < 64)  lossAcc[t] = 0.f;
        if (t < 128) ((int4*)gcnt)[t] = (int4){0, 0, 0, 0};
        if (t == 0)  gdone[0] = 0;
    }
}

// ---------------------------------------------------------------------------
// F: fused argmin GEMM (M=32768,N=1024,K=256) + gather + loss + hist.
// N-QUARTER blocks: grid 2048 = 512 position-groups x 4 code-quarters.
// R6->R7 showed shorter-blocks-more-blocks is the only lever that moved
// fused time (100->88) while occupancy stays pinned ~19% (true wave cap
// ~8/CU: unified-RF AGPR footprint not visible in VGPR_Count). This round
// pushes the same trend: 4 tiles/block (was 8), grid 2048.
// h = blockIdx&3: the 4 contributors of a group are dispatch-adjacent ->
// they stream the SAME z A-tile (cache-hot, no FETCH blowup) and the owner
// (4th finisher via gcnt) starts the epilogue promptly.
// Tile-0 B prefetch is issued before the A-stage z loads: 24 independent
// loads in flight from instruction 0.
// Merge: packed u64 atomicMin (order-preserving float map, low32=code ->
// exact first-min tie-break); owner does hist+epilogue; 512th owner
// finalizes loss+perplexity (all machinery proven R7, passed).
// ---------------------------------------------------------------------------
__global__ __launch_bounds__(256, 2) void fused_kernel(
        const float* __restrict__ z, const float* __restrict__ emb,
        const unsigned short* __restrict__ embB, const float* __restrict__ enormG,
        float* __restrict__ zq, int* __restrict__ hist,
        float* __restrict__ lossAcc, int* __restrict__ gcnt,
        int* __restrict__ gdone, unsigned long long* __restrict__ best64,
        float* __restrict__ out) {
    __shared__ __align__(16) unsigned short smem[BUFS];   // As / Bs union, 33.8 KB
    __shared__ float Ens[256];
    __shared__ float rv[2][64];
    __shared__ int   ri[2][64];
    __shared__ int   idxm[64];
    __shared__ int   amOwner, amLast;
    __shared__ float lsum[4], wsum[4];

    int t = threadIdx.x;                   // 0..255
    int h = blockIdx.x & 3;                // code quarter (adjacent twins)
    int g = blockIdx.x >> 2;               // position group 0..511
    int m0 = g * 64;
    int b = m0 >> 10, pb = m0 & 1023;
    const float* zb  = z  + (size_t)b * BSTRIDE + pb;
    float*       zqb = zq + (size_t)b * BSTRIDE + pb;

    // tile-0 B prefetch FIRST: independent of all LDS work
    const short8* eB8 = (const short8*)embB + (size_t)(h * 256) * 32;
    short8 pref[8];
#pragma unroll
    for (int i = 0; i < 8; ++i) {
        int slot = i * 256 + t;
        pref[i] = eB8[(size_t)(slot >> 5) * 32 + (slot & 31)];
    }

    Ens[t] = enormG[h * 256 + t];

    int pq = t & 15, cg = t >> 4;          // p-quad 0..15, 16-ch group 0..15
    {   // stage A: 64 pos x 256 ch, float4 loads along p, short8 LDS writes
        const float* zp = zb + pq * 4;
#pragma unroll
        for (int hh = 0; hh < 2; ++hh) {
            float4 zv[8];
#pragma unroll
            for (int v = 0; v < 8; ++v)
                zv[v] = *(const float4*)&zp[(size_t)(cg * 16 + hh * 8 + v) * HW];
#pragma unroll
            for (int j = 0; j < 4; ++j) {
                short8 w8;
#pragma unroll
                for (int v = 0; v < 8; ++v) {
                    float x = (j == 0) ? zv[v].x : (j == 1) ? zv[v].y
                            : (j == 2) ? zv[v].z : zv[v].w;
                    w8[v] = (short)f2bf(x);
                }
                *(short8*)&smem[(pq * 4 + j) * 264 + cg * 16 + hh * 8] = w8;
            }
        }
    }
    __syncthreads();

    int w = t >> 6, l = t & 63, lm = l & 15, q = l >> 4;
    int mw = w >> 1, nw = w & 1;           // mw: 32-pos half, nw: 32-code half

    short8 A[2][8];                        // all 64 pos (2 m-frags x 8 k-slices)
#pragma unroll
    for (int s = 0; s < 2; ++s)
#pragma unroll
        for (int ks = 0; ks < 8; ++ks)
            A[s][ks] = *(const short8*)&smem[(mw * 32 + s * 16 + lm) * 264 + ks * 32 + q * 8];

    float bd[8]; int bi[8];
#pragma unroll
    for (int i = 0; i < 8; ++i) { bd[i] = FLT_MAX; bi[i] = 0x7fffffff; }

    __syncthreads();   // A consumed; smem becomes the B tile buffer

    {   // write tile 0
        short8* Bw = (short8*)smem;
#pragma unroll
        for (int i = 0; i < 8; ++i) {
            int slot = i * 256 + t;
            Bw[(slot >> 5) * 33 + (slot & 31)] = pref[i];
        }
    }

#pragma unroll
    for (int nt = 0; nt < NT; ++nt) {
        __syncthreads();                   // tile nt writes visible
        if (nt < NT - 1) {                 // prefetch next tile -> regs
            int n1 = (nt + 1) * 64;
#pragma unroll
            for (int i = 0; i < 8; ++i) {
                int slot = i * 256 + t;
                pref[i] = eB8[(size_t)(n1 + (slot >> 5)) * 32 + (slot & 31)];
            }
        }
        int n0 = nt * 64;
#pragma unroll
        for (int nf = 0; nf < 2; ++nf) {
            int cl = nw * 32 + nf * 16 + lm;
            float en = Ens[n0 + cl];
            f32x4 a0a = {0,0,0,0}, a0b = {0,0,0,0};
            f32x4 a1a = {0,0,0,0}, a1b = {0,0,0,0};
#pragma unroll
            for (int ks = 0; ks < 8; ks += 2) {
                short8 Bv0 = *(const short8*)&smem[cl * 264 + ks * 32 + q * 8];
                short8 Bv1 = *(const short8*)&smem[cl * 264 + (ks + 1) * 32 + q * 8];
                a0a = __builtin_amdgcn_mfma_f32_16x16x32_bf16(A[0][ks],     Bv0, a0a, 0, 0, 0);
                a1a = __builtin_amdgcn_mfma_f32_16x16x32_bf16(A[1][ks],     Bv0, a1a, 0, 0, 0);
                a0b = __builtin_amdgcn_mfma_f32_16x16x32_bf16(A[0][ks + 1], Bv1, a0b, 0, 0, 0);
                a1b = __builtin_amdgcn_mfma_f32_16x16x32_bf16(A[1][ks + 1], Bv1, a1b, 0, 0, 0);
            }
            int code = h * 256 + n0 + cl;
#pragma unroll
            for (int r = 0; r < 4; ++r) {
                float d0 = en - 2.f * (a0a[r] + a0b[r]);
                if (d0 < bd[r])     { bd[r] = d0;     bi[r] = code; }
                float d1 = en - 2.f * (a1a[r] + a1b[r]);
                if (d1 < bd[4 + r]) { bd[4 + r] = d1; bi[4 + r] = code; }
            }
        }
        __syncthreads();                   // tile nt consumed
        if (nt < NT - 1) {                 // drain prefetch into the buffer
            short8* Bw = (short8*)smem;
#pragma unroll
            for (int i = 0; i < 8; ++i) {
                int slot = i * 256 + t;
                Bw[(slot >> 5) * 33 + (slot & 31)] = pref[i];
            }
        }
    }

    // reduce across the 16 code-columns (lanes sharing q)
#pragma unroll
    for (int off = 1; off < 16; off <<= 1) {
#pragma unroll
        for (int i = 0; i < 8; ++i) {
            float od = __shfl_xor(bd[i], off, 64);
            int   oi = __shfl_xor(bi[i], off, 64);
            if (od < bd[i] || (od == bd[i] && oi < bi[i])) { bd[i] = od; bi[i] = oi; }
        }
    }
    if (lm == 0) {
#pragma unroll
        for (int s = 0; s < 2; ++s)
#pragma unroll
            for (int r = 0; r < 4; ++r) {
                int p = mw * 32 + s * 16 + q * 4 + r;
                rv[nw][p] = bd[s * 4 + r];
                ri[nw][p] = bi[s * 4 + r];
            }
    }
    __syncthreads();
    if (t < 64) {   // merge nw halves, publish to global packed argmin
        float v0 = rv[0][t]; int i0 = ri[0][t];
        float v1 = rv[1][t]; int i1 = ri[1][t];
        float v = (v1 < v0 || (v1 == v0 && i1 < i0)) ? v1 : v0;
        int bix  = (v1 < v0 || (v1 == v0 && i1 < i0)) ? i1 : i0;
        unsigned ub = __builtin_bit_cast(unsigned, v);
        ub = (ub & 0x80000000u) ? ~ub : (ub | 0x80000000u);   // order-preserving
        unsigned long long pk = ((unsigned long long)ub << 32) | (unsigned)bix;
        atomicMin(&best64[(size_t)g * 64 + t], pk);
    }
    __syncthreads();
    if (t == 0) {
        __threadfence();
        amOwner = (atomicAdd(&gcnt[g], 1) == 3);   // 4th finisher owns epilogue
    }
    __syncthreads();
    if (!amOwner) return;

    if (t < 64) {   // read merged winners (atomic read = coherent point)
        unsigned long long pk = atomicAdd(&best64[(size_t)g * 64 + t], 0ULL);
        int code = (int)(pk & 0xFFFFFFFFull);
        idxm[t] = code;
        atomicAdd(&hist[code], 1);
    }
    __syncthreads();

    {   // epilogue: gather 4 emb rows x 16 ch, re-read z, write z_q, loss
        int p0 = pq * 4;
        int k0 = idxm[p0], k1 = idxm[p0 + 1], k2 = idxm[p0 + 2], k3 = idxm[p0 + 3];
        float ls = 0.f;
#pragma unroll
        for (int hh = 0; hh < 2; ++hh) {
            int cb = cg * 16 + hh * 8;
            float e0[8], e1[8], e2[8], e3[8];
            {
                const float4* a = (const float4*)(emb + (size_t)k0 * EDIM) + (cb >> 2);
                *(float4*)&e0[0] = a[0]; *(float4*)&e0[4] = a[1];
            }
            {
                const float4* a = (const float4*)(emb + (size_t)k1 * EDIM) + (cb >> 2);
                *(float4*)&e1[0] = a[0]; *(float4*)&e1[4] = a[1];
            }
            {
                const float4* a = (const float4*)(emb + (size_t)k2 * EDIM) + (cb >> 2);
                *(float4*)&e2[0] = a[0]; *(float4*)&e2[4] = a[1];
            }
            {
                const float4* a = (const float4*)(emb + (size_t)k3 * EDIM) + (cb >> 2);
                *(float4*)&e3[0] = a[0]; *(float4*)&e3[4] = a[1];
            }
            float zr[32];
#pragma unroll
            for (int v = 0; v < 8; ++v)
                *(float4*)&zr[v * 4] = *(const float4*)&zb[(size_t)(cb + v) * HW + p0];
#pragma unroll
            for (int v = 0; v < 8; ++v) {
                float4 qv; qv.x = e0[v]; qv.y = e1[v]; qv.z = e2[v]; qv.w = e3[v];
                *(float4*)&zqb[(size_t)(cb + v) * HW + p0] = qv;
                float dx = qv.x - zr[v * 4 + 0], dy = qv.y - zr[v * 4 + 1];
                float dz = qv.z - zr[v * 4 + 2], dw = qv.w - zr[v * 4 + 3];
                ls += dx * dx + dy * dy + dz * dz + dw * dw;
            }
        }
#pragma unroll
        for (int off = 32; off; off >>= 1) ls += __shfl_down(ls, off, 64);
        if ((t & 63) == 0) lsum[w] = ls;
    }
    __syncthreads();
    if (t == 0) {   // ONE loss atomic per owner block, 64-banked
        atomicAdd(&lossAcc[g & 63], lsum[0] + lsum[1] + lsum[2] + lsum[3]);
        __threadfence();
        amLast = (atomicAdd(gdone, 1) == 511);
    }
    __syncthreads();
    if (amLast) {
        float s = 0.f;
        for (int j = t; j < NE; j += 256) {
            float p = (float)atomicAdd(&hist[j], 0) * (1.0f / 32768.0f);
            s += p * logf(p + 1e-10f);
        }
#pragma unroll
        for (int off = 32; off; off >>= 1) s += __shfl_down(s, off, 64);
        if ((t & 63) == 0) wsum[t >> 6] = s;
        float lt = 0.f;
        if (t < 64) lt = atomicAdd(&lossAcc[t], 0.f);
#pragma unroll
        for (int off = 32; off; off >>= 1) lt += __shfl_down(lt, off, 64);
        __syncthreads();
        if (t == 0) {
            float S = wsum[0] + wsum[1] + wsum[2] + wsum[3];
            out[TOTAL]     = 1.25f * lt / (float)TOTAL;
            out[TOTAL + 1] = expf(-S);
        }
    }
}

extern "C" void kernel_launch(void* const* d_in, const int* in_sizes, int n_in,
                              void* d_out, int out_size, void* d_ws, size_t ws_size,
                              hipStream_t stream) {
    (void)in_sizes; (void)n_in; (void)out_size; (void)ws_size;
    const float* z   = (const float*)d_in[0];
    const float* emb = (const float*)d_in[1];
    float* out = (float*)d_out;
    char* ws = (char*)d_ws;
    unsigned short* embB = (unsigned short*)(ws + EMBB_OFF);
    float* enorm   = (float*)(ws + ENORM_OFF);
    int*   hist    = (int*)(ws + HIST_OFF);
    float* lossAcc = (float*)(ws + LOSS_OFF);
    int*   gcnt    = (int*)(ws + GCNT_OFF);
    int*   gdone   = (int*)(ws + GDONE_OFF);
    unsigned long long* best64 = (unsigned long long*)(ws + BEST_OFF);

    prep_emb<<<64, 256, 0, stream>>>(emb, embB, enorm, hist, lossAcc,
                                     gcnt, gdone, best64);
    fused_kernel<<<2048, 256, 0, stream>>>(z, emb, embB, enorm, out, hist,
                                           lossAcc, gcnt, gdone, best64, out);
}

// Round 9
// 155.152 us; speedup vs baseline: 1.6523x; 1.6523x over previous
//
#include <hip/hip_runtime.h>
#include <cfloat>

typedef __attribute__((ext_vector_type(8))) short short8;
typedef __attribute__((ext_vector_type(4))) float f32x4;

#define NE 1024
#define EDIM 256
#define HW 1024
#define BSTRIDE (EDIM * HW)        // 262144
#define TOTAL 8388608

// workspace layout (bytes)
#define EMBB_OFF  0                        // ushort[1024*256] bf16 = 512 KB
#define ENORM_OFF (512 * 1024)             // float[1024]
#define HIST_OFF  (ENORM_OFF + 4096)       // int[1024]
#define LOSS_OFF  (HIST_OFF + 4096)        // float[64] banked loss accum
#define GCNT_OFF  (LOSS_OFF + 256)         // int[512] per-group twin counter
#define GDONE_OFF (GCNT_OFF + 2048)        // int completion counter
#define BEST_OFF  (GDONE_OFF + 16)         // u64[32768] packed (dist,code)

#define BUFS (64 * 264)                    // shorts per A or B buffer

// round-to-nearest-even fp32 -> bf16 bits (inputs are finite)
__device__ __forceinline__ unsigned short f2bf(float x) {
    unsigned u = __builtin_bit_cast(unsigned, x);
    return (unsigned short)((u + 0x7fffu + ((u >> 16) & 1u)) >> 16);
}
__device__ __forceinline__ float bf2f(unsigned short b) {
    return __builtin_bit_cast(float, (unsigned)b << 16);
}

// ---------------------------------------------------------------------------
// P: emb fp32 [1024][256] -> embB bf16 rows + enorm. 64 blocks x 256 thr.
// Also inits best64 (all blocks) and hist/loss/gcnt/gdone (block 0).
// ---------------------------------------------------------------------------
__global__ void prep_emb(const float* __restrict__ emb,
                         unsigned short* __restrict__ embB,
                         float* __restrict__ enorm,
                         int* __restrict__ hist,
                         float* __restrict__ lossAcc,
                         int* __restrict__ gcnt,
                         int* __restrict__ gdone,
                         unsigned long long* __restrict__ best64) {
    int t = threadIdx.x;
    int gid = blockIdx.x * 256 + t;        // 0..16383
    int row = gid >> 4, seg = gid & 15;
    const float4* e4 = (const float4*)(emb + (size_t)row * EDIM) + seg * 4;
    float4 a0 = e4[0], a1 = e4[1], a2 = e4[2], a3 = e4[3];
    float s = a0.x * a0.x + a0.y * a0.y + a0.z * a0.z + a0.w * a0.w
            + a1.x * a1.x + a1.y * a1.y + a1.z * a1.z + a1.w * a1.w
            + a2.x * a2.x + a2.y * a2.y + a2.z * a2.z + a2.w * a2.w
            + a3.x * a3.x + a3.y * a3.y + a3.z * a3.z + a3.w * a3.w;
    short8 v0, v1;
    v0[0] = (short)f2bf(a0.x); v0[1] = (short)f2bf(a0.y);
    v0[2] = (short)f2bf(a0.z); v0[3] = (short)f2bf(a0.w);
    v0[4] = (short)f2bf(a1.x); v0[5] = (short)f2bf(a1.y);
    v0[6] = (short)f2bf(a1.z); v0[7] = (short)f2bf(a1.w);
    v1[0] = (short)f2bf(a2.x); v1[1] = (short)f2bf(a2.y);
    v1[2] = (short)f2bf(a2.z); v1[3] = (short)f2bf(a2.w);
    v1[4] = (short)f2bf(a3.x); v1[5] = (short)f2bf(a3.y);
    v1[6] = (short)f2bf(a3.z); v1[7] = (short)f2bf(a3.w);
    *(short8*)&embB[(size_t)row * EDIM + seg * 16]     = v0;
    *(short8*)&embB[(size_t)row * EDIM + seg * 16 + 8] = v1;
    s += __shfl_xor(s, 1, 64);
    s += __shfl_xor(s, 2, 64);
    s += __shfl_xor(s, 4, 64);
    s += __shfl_xor(s, 8, 64);
    if (seg == 0) enorm[row] = s;
    // best64 init: 64 blocks x 256 thr x 2 = 32768
    size_t b0 = (size_t)blockIdx.x * 512 + (size_t)t * 2;
    best64[b0] = ~0ULL; best64[b0 + 1] = ~0ULL;
    if (blockIdx.x == 0) {
        ((int4*)hist)[t] = (int4){0, 0, 0, 0};
        if (t < 64)  lossAcc[t] = 0.f;
        if (t < 128) ((int4*)gcnt)[t] = (int4){0, 0, 0, 0};
        if (t == 0)  gdone[0] = 0;
    }
}

// ---------------------------------------------------------------------------
// F: fused argmin GEMM (M=32768,N=1024,K=256) + gather + loss + hist.
// R7 structure (best fused: 88us) with two counter-driven fixes:
//  1. XCD-aware twin pairing: h=(bid>>3)&1, g=(bid&7)|((bid>>4)<<3).
//     The two code-half twins of a group differ by exactly 8 in blockIdx
//     -> SAME XCD (blocks round-robin over 8 XCDs), back-to-back dispatch
//     -> the 2nd twin's 64KB z A-stage is L2-hit, not a 2nd HBM stream.
//     (R8's 4-way split with bid&3 pairing put contributors on 4 DIFFERENT
//     XCDs: FETCH 45->86MB, 620GB/s BW-starved, 203us. The split count was
//     never the lever; split x cache-placement is.)
//  2. Owner epilogue computes loss from the bf16 A-tile kept in LDS
//     (separate As buffer, no A/B union; 70KB still = 2 blocks/CU, which
//     is all the unified-RF register cap allows anyway). Deletes the 16
//     float4 global z re-reads per thread (~33MB round-trips + a full
//     latency phase). bf16-z loss error ~1e-5 rel << passing 1.9e-3.
// Merge machinery byte-identical to R7 (passed): packed u64 atomicMin,
// order-preserving float map, 2nd-finisher owner, 512th-owner finalize.
// ---------------------------------------------------------------------------
__global__ __launch_bounds__(256, 2) void fused_kernel(
        const float* __restrict__ z, const float* __restrict__ emb,
        const unsigned short* __restrict__ embB, const float* __restrict__ enormG,
        float* __restrict__ zq, int* __restrict__ hist,
        float* __restrict__ lossAcc, int* __restrict__ gcnt,
        int* __restrict__ gdone, unsigned long long* __restrict__ best64,
        float* __restrict__ out) {
    __shared__ __align__(16) unsigned short As[BUFS];   // 33.8 KB, lives whole kernel
    __shared__ __align__(16) unsigned short Bs[BUFS];   // 33.8 KB B tile
    __shared__ float Ens[512];
    __shared__ float rv[2][64];
    __shared__ int   ri[2][64];
    __shared__ int   idxm[64];
    __shared__ int   amOwner, amLast;
    __shared__ float lsum[4], wsum[4];

    int t = threadIdx.x;                   // 0..255
    int bid = blockIdx.x;
    int h = (bid >> 3) & 1;                // code half; twins differ by +8 -> same XCD
    int g = (bid & 7) | ((bid >> 4) << 3); // position group 0..511 (bijective)
    int m0 = g * 64;
    int b = m0 >> 10, pb = m0 & 1023;
    const float* zb  = z  + (size_t)b * BSTRIDE + pb;
    float*       zqb = zq + (size_t)b * BSTRIDE + pb;

    // tile-0 B prefetch FIRST: independent of all LDS work
    const short8* eB8 = (const short8*)embB + (size_t)(h * 512) * 32;
    short8 pref[8];
#pragma unroll
    for (int i = 0; i < 8; ++i) {
        int slot = i * 256 + t;
        pref[i] = eB8[(size_t)(slot >> 5) * 32 + (slot & 31)];
    }

    for (int j = t; j < 512; j += 256) Ens[j] = enormG[h * 512 + j];

    int pq = t & 15, cg = t >> 4;          // p-quad 0..15, 16-ch group 0..15
    {   // stage A: 64 pos x 256 ch, float4 loads along p, short8 LDS writes
        const float* zp = zb + pq * 4;
#pragma unroll
        for (int hh = 0; hh < 2; ++hh) {
            float4 zv[8];
#pragma unroll
            for (int v = 0; v < 8; ++v)
                zv[v] = *(const float4*)&zp[(size_t)(cg * 16 + hh * 8 + v) * HW];
#pragma unroll
            for (int j = 0; j < 4; ++j) {
                short8 w8;
#pragma unroll
                for (int v = 0; v < 8; ++v) {
                    float x = (j == 0) ? zv[v].x : (j == 1) ? zv[v].y
                            : (j == 2) ? zv[v].z : zv[v].w;
                    w8[v] = (short)f2bf(x);
                }
                *(short8*)&As[(pq * 4 + j) * 264 + cg * 16 + hh * 8] = w8;
            }
        }
    }
    {   // tile-0 into Bs needs no barrier: disjoint buffer from As
        short8* Bw = (short8*)Bs;
#pragma unroll
        for (int i = 0; i < 8; ++i) {
            int slot = i * 256 + t;
            Bw[(slot >> 5) * 33 + (slot & 31)] = pref[i];
        }
    }
    __syncthreads();

    int w = t >> 6, l = t & 63, lm = l & 15, q = l >> 4;
    int mw = w >> 1, nw = w & 1;           // mw: 32-pos half, nw: 32-code half

    short8 A[2][8];                        // all 64 pos (2 m-frags x 8 k-slices)
#pragma unroll
    for (int s = 0; s < 2; ++s)
#pragma unroll
        for (int ks = 0; ks < 8; ++ks)
            A[s][ks] = *(const short8*)&As[(mw * 32 + s * 16 + lm) * 264 + ks * 32 + q * 8];

    float bd[8]; int bi[8];
#pragma unroll
    for (int i = 0; i < 8; ++i) { bd[i] = FLT_MAX; bi[i] = 0x7fffffff; }

#pragma unroll 2
    for (int nt = 0; nt < 8; ++nt) {
        if (nt) __syncthreads();           // tile nt writes visible (tile0 covered above)
        if (nt < 7) {                      // prefetch next tile -> regs
            int n1 = (nt + 1) * 64;
#pragma unroll
            for (int i = 0; i < 8; ++i) {
                int slot = i * 256 + t;
                pref[i] = eB8[(size_t)(n1 + (slot >> 5)) * 32 + (slot & 31)];
            }
        }
        int n0 = nt * 64;
#pragma unroll
        for (int nf = 0; nf < 2; ++nf) {
            int cl = nw * 32 + nf * 16 + lm;
            float en = Ens[n0 + cl];
            f32x4 a0a = {0,0,0,0}, a0b = {0,0,0,0};
            f32x4 a1a = {0,0,0,0}, a1b = {0,0,0,0};
#pragma unroll
            for (int ks = 0; ks < 8; ks += 2) {
                short8 Bv0 = *(const short8*)&Bs[cl * 264 + ks * 32 + q * 8];
                short8 Bv1 = *(const short8*)&Bs[cl * 264 + (ks + 1) * 32 + q * 8];
                a0a = __builtin_amdgcn_mfma_f32_16x16x32_bf16(A[0][ks],     Bv0, a0a, 0, 0, 0);
                a1a = __builtin_amdgcn_mfma_f32_16x16x32_bf16(A[1][ks],     Bv0, a1a, 0, 0, 0);
                a0b = __builtin_amdgcn_mfma_f32_16x16x32_bf16(A[0][ks + 1], Bv1, a0b, 0, 0, 0);
                a1b = __builtin_amdgcn_mfma_f32_16x16x32_bf16(A[1][ks + 1], Bv1, a1b, 0, 0, 0);
            }
            int code = h * 512 + n0 + cl;
#pragma unroll
            for (int r = 0; r < 4; ++r) {
                float d0 = en - 2.f * (a0a[r] + a0b[r]);
                if (d0 < bd[r])     { bd[r] = d0;     bi[r] = code; }
                float d1 = en - 2.f * (a1a[r] + a1b[r]);
                if (d1 < bd[4 + r]) { bd[4 + r] = d1; bi[4 + r] = code; }
            }
        }
        __syncthreads();                   // tile nt consumed
        if (nt < 7) {                      // drain prefetch into the buffer
            short8* Bw = (short8*)Bs;
#pragma unroll
            for (int i = 0; i < 8; ++i) {
                int slot = i * 256 + t;
                Bw[(slot >> 5) * 33 + (slot & 31)] = pref[i];
            }
        }
    }

    // reduce across the 16 code-columns (lanes sharing q)
#pragma unroll
    for (int off = 1; off < 16; off <<= 1) {
#pragma unroll
        for (int i = 0; i < 8; ++i) {
            float od = __shfl_xor(bd[i], off, 64);
            int   oi = __shfl_xor(bi[i], off, 64);
            if (od < bd[i] || (od == bd[i] && oi < bi[i])) { bd[i] = od; bi[i] = oi; }
        }
    }
    if (lm == 0) {
#pragma unroll
        for (int s = 0; s < 2; ++s)
#pragma unroll
            for (int r = 0; r < 4; ++r) {
                int p = mw * 32 + s * 16 + q * 4 + r;
                rv[nw][p] = bd[s * 4 + r];
                ri[nw][p] = bi[s * 4 + r];
            }
    }
    __syncthreads();
    if (t < 64) {   // merge nw halves, publish to global packed argmin
        float v0 = rv[0][t]; int i0 = ri[0][t];
        float v1 = rv[1][t]; int i1 = ri[1][t];
        float v = (v1 < v0 || (v1 == v0 && i1 < i0)) ? v1 : v0;
        int bix  = (v1 < v0 || (v1 == v0 && i1 < i0)) ? i1 : i0;
        unsigned ub = __builtin_bit_cast(unsigned, v);
        ub = (ub & 0x80000000u) ? ~ub : (ub | 0x80000000u);   // order-preserving
        unsigned long long pk = ((unsigned long long)ub << 32) | (unsigned)bix;
        atomicMin(&best64[(size_t)g * 64 + t], pk);
    }
    __syncthreads();
    if (t == 0) {
        __threadfence();
        amOwner = (atomicAdd(&gcnt[g], 1) == 1);   // 2nd finisher owns epilogue
    }
    __syncthreads();
    if (!amOwner) return;

    if (t < 64) {   // read merged winners (atomic read = coherent point)
        unsigned long long pk = atomicAdd(&best64[(size_t)g * 64 + t], 0ULL);
        int code = (int)(pk & 0xFFFFFFFFull);
        idxm[t] = code;
        atomicAdd(&hist[code], 1);
    }
    __syncthreads();

    {   // epilogue: gather 4 emb rows x 16 ch, z from LDS bf16 A-tile,
        // write z_q (float4 along p), accumulate loss. NO global z re-read.
        int p0 = pq * 4;
        int k0 = idxm[p0], k1 = idxm[p0 + 1], k2 = idxm[p0 + 2], k3 = idxm[p0 + 3];
        float ls = 0.f;
#pragma unroll
        for (int hh = 0; hh < 2; ++hh) {
            int cb = cg * 16 + hh * 8;
            float e0[8], e1[8], e2[8], e3[8];
            {
                const float4* a = (const float4*)(emb + (size_t)k0 * EDIM) + (cb >> 2);
                *(float4*)&e0[0] = a[0]; *(float4*)&e0[4] = a[1];
            }
            {
                const float4* a = (const float4*)(emb + (size_t)k1 * EDIM) + (cb >> 2);
                *(float4*)&e1[0] = a[0]; *(float4*)&e1[4] = a[1];
            }
            {
                const float4* a = (const float4*)(emb + (size_t)k2 * EDIM) + (cb >> 2);
                *(float4*)&e2[0] = a[0]; *(float4*)&e2[4] = a[1];
            }
            {
                const float4* a = (const float4*)(emb + (size_t)k3 * EDIM) + (cb >> 2);
                *(float4*)&e3[0] = a[0]; *(float4*)&e3[4] = a[1];
            }
            short8 zs0 = *(const short8*)&As[(p0 + 0) * 264 + cb];
            short8 zs1 = *(const short8*)&As[(p0 + 1) * 264 + cb];
            short8 zs2 = *(const short8*)&As[(p0 + 2) * 264 + cb];
            short8 zs3 = *(const short8*)&As[(p0 + 3) * 264 + cb];
#pragma unroll
            for (int v = 0; v < 8; ++v) {
                float4 qv; qv.x = e0[v]; qv.y = e1[v]; qv.z = e2[v]; qv.w = e3[v];
                *(float4*)&zqb[(size_t)(cb + v) * HW + p0] = qv;
                float dx = qv.x - bf2f((unsigned short)zs0[v]);
                float dy = qv.y - bf2f((unsigned short)zs1[v]);
                float dz = qv.z - bf2f((unsigned short)zs2[v]);
                float dw = qv.w - bf2f((unsigned short)zs3[v]);
                ls += dx * dx + dy * dy + dz * dz + dw * dw;
            }
        }
#pragma unroll
        for (int off = 32; off; off >>= 1) ls += __shfl_down(ls, off, 64);
        if ((t & 63) == 0) lsum[w] = ls;
    }
    __syncthreads();
    if (t == 0) {   // ONE loss atomic per owner block, 64-banked
        atomicAdd(&lossAcc[g & 63], lsum[0] + lsum[1] + lsum[2] + lsum[3]);
        __threadfence();
        amLast = (atomicAdd(gdone, 1) == 511);
    }
    __syncthreads();
    if (amLast) {
        float s = 0.f;
        for (int j = t; j < NE; j += 256) {
            float p = (float)atomicAdd(&hist[j], 0) * (1.0f / 32768.0f);
            s += p * logf(p + 1e-10f);
        }
#pragma unroll
        for (int off = 32; off; off >>= 1) s += __shfl_down(s, off, 64);
        if ((t & 63) == 0) wsum[t >> 6] = s;
        float lt = 0.f;
        if (t < 64) lt = atomicAdd(&lossAcc[t], 0.f);
#pragma unroll
        for (int off = 32; off; off >>= 1) lt += __shfl_down(lt, off, 64);
        __syncthreads();
        if (t == 0) {
            float S = wsum[0] + wsum[1] + wsum[2] + wsum[3];
            out[TOTAL]     = 1.25f * lt / (float)TOTAL;
            out[TOTAL + 1] = expf(-S);
        }
    }
}

extern "C" void kernel_launch(void* const* d_in, const int* in_sizes, int n_in,
                              void* d_out, int out_size, void* d_ws, size_t ws_size,
                              hipStream_t stream) {
    (void)in_sizes; (void)n_in; (void)out_size; (void)ws_size;
    const float* z   = (const float*)d_in[0];
    const float* emb = (const float*)d_in[1];
    float* out = (float*)d_out;
    char* ws = (char*)d_ws;
    unsigned short* embB = (unsigned short*)(ws + EMBB_OFF);
    float* enorm   = (float*)(ws + ENORM_OFF);
    int*   hist    = (int*)(ws + HIST_OFF);
    float* lossAcc = (float*)(ws + LOSS_OFF);
    int*   gcnt    = (int*)(ws + GCNT_OFF);
    int*   gdone   = (int*)(ws + GDONE_OFF);
    unsigned long long* best64 = (unsigned long long*)(ws + BEST_OFF);

    prep_emb<<<64, 256, 0, stream>>>(emb, embB, enorm, hist, lossAcc,
                                     gcnt, gdone, best64);
    fused_kernel<<<1024, 256, 0, stream>>>(z, emb, embB, enorm, out, hist,
                                           lossAcc, gcnt, gdone, best64, out);
}